// Round 8
// baseline (1651.731 us; speedup 1.0000x reference)
//
#include <hip/hip_runtime.h>

typedef _Float16 f16;
typedef _Float16 f16x8 __attribute__((ext_vector_type(8)));
typedef float f32x4 __attribute__((ext_vector_type(4)));
typedef unsigned int u32;
typedef const __attribute__((address_space(1))) u32* gas1_t;
typedef __attribute__((address_space(3))) u32* las3_t;

#define WGRAN 460800   // 225 * 2048 granules of 8 halves (W)
#define IGRAN 32768    // 262144/8 granules (inp)

// fp32 -> f16 with W permuted into the fragment-ready layout:
// W_h[dxdy][i][o][quad] (granules of 8 halves) = W[dxdy][o][i][quad*8+u]
__global__ __launch_bounds__(256) void convert_kernel(
    const float* __restrict__ W, const float* __restrict__ inp,
    f16* __restrict__ W_h, f16* __restrict__ inp_h)
{
    const int g = blockIdx.x * 256 + threadIdx.x;   // grid sized exactly
    if (g < WGRAN) {
        const int dxdy = g >> 11;
        const int r = g & 2047;
        const int i = r >> 6, o = (r >> 2) & 15, quad = r & 3;
        const float* src = W + (size_t)dxdy * 16384 + o * 1024 + i * 32 + quad * 8;
        const float4 v0 = *(const float4*)src;
        const float4 v1 = *(const float4*)(src + 4);
        f16x8 h = { (f16)v0.x, (f16)v0.y, (f16)v0.z, (f16)v0.w,
                    (f16)v1.x, (f16)v1.y, (f16)v1.z, (f16)v1.w };
        *(f16x8*)(W_h + (size_t)g * 8) = h;
    } else {
        const int k = g - WGRAN;
        const float* src = inp + (size_t)k * 8;
        const float4 v0 = *(const float4*)src;
        const float4 v1 = *(const float4*)(src + 4);
        f16x8 h = { (f16)v0.x, (f16)v0.y, (f16)v0.z, (f16)v0.w,
                    (f16)v1.x, (f16)v1.y, (f16)v1.z, (f16)v1.w };
        *(f16x8*)(inp_h + (size_t)k * 8) = h;
    }
}

// R8 PMC-VISIBILITY PROBE: R4 structure (best known, ~28 us/launch by R6's
// marginal-cost measurement; R7's 128-thr variant regressed and is reverted),
// body wrapped in an idempotent x4 repeat so the single dispatch runs ~110 us
// and lands in the profiler top-5 WITH counters (the ~46 us harness fills
// otherwise mask it). Decision rule is pre-committed in the journal:
// WRITE amp -> Y-pair line stores; FETCH amp -> L3 thrash fix; VALUBusy>60 ->
// reduce pk_mul; all-low+low-occ -> counted-vmcnt pipeline.
__global__ __launch_bounds__(256, 2) void rel_mfma4r(
    const f16* __restrict__ W_h,    // [dxdy][i][o][quad][8]
    const f16* __restrict__ inp_h,  // (128,8,8,32) f16
    const float* __restrict__ bias, // (15,15,16)
    float* __restrict__ out)        // (128,8,8,8,8,16)
{
    extern __shared__ __align__(16) f16 Wl[];   // 2 x 32768 B

    const int hw = blockIdx.x;                  // 512 = (x,y,X), X fastest
    const int X = hw & 7, y = (hw >> 3) & 7, x = (hw >> 6) & 7;
    const int dx = X - x + 7;

    const int t = threadIdx.x;
    const int lane = t & 63;
    const int wave = t >> 6;       // 0..3 -> b-tiles 2w, 2w+1
    const int quad = lane >> 4;
    const int m = lane & 15;       // A-row (b%16) and B-col (o)

    // 8 tiles for Y=0..7 start at dxdy = dx*15 + (7-y), contiguous.
    const f16* wbase = W_h + (size_t)(dx * 15 + 7 - y) * 16384;

    // ---- a-rows (Y-invariant) + all 8 c-frags into registers (rep-invariant)
    f16x8 a0[4], a1[4], c0[8], c1[8];
    const int b0 = wave * 32 + m;
    const int b1 = b0 + 16;
    {
        const f16* ar0 = inp_h + ((b0 * 8 + x) * 8 + y) * 32;
        const f16* ar1 = inp_h + ((b1 * 8 + x) * 8 + y) * 32;
        #pragma unroll
        for (int g = 0; g < 4; ++g) {
            a0[g] = *(const f16x8*)(ar0 + g * 8);
            a1[g] = *(const f16x8*)(ar1 + g * 8);
        }
        const f16* cr0 = inp_h + (b0 * 8 + X) * 256 + quad * 8;  // Y=0 row
        const f16* cr1 = inp_h + (b1 * 8 + X) * 256 + quad * 8;
        #pragma unroll
        for (int Yi = 0; Yi < 8; ++Yi) {
            c0[Yi] = *(const f16x8*)(cr0 + Yi * 32);
            c1[Yi] = *(const f16x8*)(cr1 + Yi * 32);
        }
    }

    const int bid_base = ((x * 8 + y) * 8 + X) * 8;   // bid = bid_base + Y

    #pragma unroll 1   // rep loop: idempotent x4 repeat, no code bloat
    for (int rep = 0; rep < 4; ++rep) {

        // ---- stage tile Y=0 into buffer 0 ----
        #pragma unroll
        for (int it = 0; it < 8; ++it) {
            const int idx = (it * 256 + t) * 8;          // 16 B granule
            __builtin_amdgcn_global_load_lds((gas1_t)(wbase + idx),
                                             (las3_t)&Wl[idx], 16, 0, 0);
        }
        __syncthreads();   // drains vmcnt -> tile 0 in LDS

        #pragma unroll     // full unroll: keeps c0[Y]/c1[Y] statically indexed
        for (int Y = 0; Y < 8; ++Y) {
            const int cur = Y & 1;

            // ---- issue prefetch of tile Y+1 into the other buffer ----
            if (Y < 7) {
                const f16* nbase = wbase + (size_t)(Y + 1) * 16384;
                f16* ldst = Wl + (cur ^ 1) * 16384;
                #pragma unroll
                for (int it = 0; it < 8; ++it) {
                    const int idx = (it * 256 + t) * 8;
                    __builtin_amdgcn_global_load_lds((gas1_t)(nbase + idx),
                                                     (las3_t)&ldst[idx], 16, 0, 0);
                }
            }

            // ---- K-loop: 32 steps, 2-deep bfrag prefetch ----
            f32x4 acc0 = {0.f, 0.f, 0.f, 0.f};
            f32x4 acc1 = {0.f, 0.f, 0.f, 0.f};
            const f16* wl = Wl + cur * 16384 + m * 32 + quad * 8;
            f16x8 bfrag = *(const f16x8*)(wl);               // kb = 0
            #pragma unroll
            for (int kb = 0; kb < 32; ++kb) {
                const f16x8 bcur = bfrag;
                if (kb < 31)
                    bfrag = *(const f16x8*)(wl + (kb + 1) * 512);
                const f16 av0 = a0[kb >> 3][kb & 7];
                const f16 av1 = a1[kb >> 3][kb & 7];
                const f16x8 af0 = c0[Y] * av0;   // P[b, kb*32 + quad*8 + r]
                const f16x8 af1 = c1[Y] * av1;
                acc0 = __builtin_amdgcn_mfma_f32_16x16x32_f16(af0, bcur, acc0, 0, 0, 0);
                acc1 = __builtin_amdgcn_mfma_f32_16x16x32_f16(af1, bcur, acc1, 0, 0, 0);
            }

            // ---- epilogue for this Y (overlaps the in-flight prefetch) ----
            const int dxdy = dx * 15 + (Y - y + 7);
            const int bid = bid_base + Y;
            const float bv = bias[dxdy * 16 + m];
            #pragma unroll
            for (int r = 0; r < 4; ++r) {
                const int bb = wave * 32 + quad * 4 + r;
                out[((size_t)bb * 4096 + bid) * 16 + m]        = acc0[r] + bv;
                out[((size_t)(bb + 16) * 4096 + bid) * 16 + m] = acc1[r] + bv;
            }

            __syncthreads();   // vmcnt drain: tile Y+1 ready; guards buffer reuse
        }
    }
}

extern "C" void kernel_launch(void* const* d_in, const int* in_sizes, int n_in,
                              void* d_out, int out_size, void* d_ws, size_t ws_size,
                              hipStream_t stream)
{
    const float* inp  = (const float*)d_in[0];  // (128,8,8,32)
    const float* W    = (const float*)d_in[1];  // (15,15,16,32,32)
    const float* bias = (const float*)d_in[2];  // (15,15,16)
    float* out = (float*)d_out;

    f16* W_h   = (f16*)d_ws;                         // 7,372,800 halves
    f16* inp_h = (f16*)d_ws + (size_t)WGRAN * 8;     //   262,144 halves

    hipLaunchKernelGGL(convert_kernel, dim3((WGRAN + IGRAN) / 256), dim3(256), 0,
                       stream, W, inp, W_h, inp_h);
    hipLaunchKernelGGL(rel_mfma4r, dim3(512), dim3(256), 65536, stream,
                       W_h, inp_h, bias, out);
}

// Round 9
// 104.414 us; speedup vs baseline: 15.8190x; 15.8190x over previous
//
#include <hip/hip_runtime.h>

typedef _Float16 f16;
typedef _Float16 f16x8 __attribute__((ext_vector_type(8)));
typedef float f32x4 __attribute__((ext_vector_type(4)));
typedef unsigned int u32;
typedef const __attribute__((address_space(1))) u32* gas1_t;
typedef __attribute__((address_space(3))) u32* las3_t;

#define WGRAN 460800   // 225 * 2048 granules of 8 halves (W)
#define IGRAN 32768    // 262144/8 granules (inp)

// fp32 -> f16 with W permuted into the fragment-ready layout:
// W_h[dxdy][i][o][quad] (granules of 8 halves) = W[dxdy][o][i][quad*8+u]
__global__ __launch_bounds__(256) void convert_kernel(
    const float* __restrict__ W, const float* __restrict__ inp,
    f16* __restrict__ W_h, f16* __restrict__ inp_h)
{
    const int g = blockIdx.x * 256 + threadIdx.x;   // grid sized exactly
    if (g < WGRAN) {
        const int dxdy = g >> 11;
        const int r = g & 2047;
        const int i = r >> 6, o = (r >> 2) & 15, quad = r & 3;
        const float* src = W + (size_t)dxdy * 16384 + o * 1024 + i * 32 + quad * 8;
        const float4 v0 = *(const float4*)src;
        const float4 v1 = *(const float4*)(src + 4);
        f16x8 h = { (f16)v0.x, (f16)v0.y, (f16)v0.z, (f16)v0.w,
                    (f16)v1.x, (f16)v1.y, (f16)v1.z, (f16)v1.w };
        *(f16x8*)(W_h + (size_t)g * 8) = h;
    } else {
        const int k = g - WGRAN;
        const float* src = inp + (size_t)k * 8;
        const float4 v0 = *(const float4*)src;
        const float4 v1 = *(const float4*)(src + 4);
        f16x8 h = { (f16)v0.x, (f16)v0.y, (f16)v0.z, (f16)v0.w,
                    (f16)v1.x, (f16)v1.y, (f16)v1.z, (f16)v1.w };
        *(f16x8*)(inp_h + (size_t)k * 8) = h;
    }
}

// R9: R4 structure + FULL-LINE OUTPUT STORES.
// R8's desync probe exposed 9x HBM write amplification: out is written as
// 64 B segments whose 128 B line-partner (bid +/- 1 = adjacent Y) is written
// by the same block one K-loop (~1.5 us) later -- right at L2 eviction age,
// so partial-line evictions + RMW fetches dominate the single-shot kernel
// too. Fix: 16 KB LDS obuf; each Y writes acc+bias into obuf[ypar][b][o];
// at odd Y all 256 threads flush the (Y-1,Y) pair as full 128 B lines
// (1024 float4 chunks, lane-contiguous, perfectly coalesced).
// LDS = 64 KB W dbuf + 16 KB obuf = 80 KB -> exactly 2 blocks/CU.
__global__ __launch_bounds__(256, 2) void rel_mfma6(
    const f16* __restrict__ W_h,    // [dxdy][i][o][quad][8]
    const f16* __restrict__ inp_h,  // (128,8,8,32) f16
    const float* __restrict__ bias, // (15,15,16)
    float* __restrict__ out)        // (128,8,8,8,8,16)
{
    extern __shared__ __align__(16) f16 Wl[];     // 65536 B W + 16384 B obuf
    float* obuf = (float*)&Wl[32768];             // [1024] float4 chunks

    const int hw = blockIdx.x;                  // 512 = (x,y,X), X fastest
    const int X = hw & 7, y = (hw >> 3) & 7, x = (hw >> 6) & 7;
    const int dx = X - x + 7;

    const int t = threadIdx.x;
    const int lane = t & 63;
    const int wave = t >> 6;       // 0..3 -> b-tiles 2w, 2w+1
    const int quad = lane >> 4;
    const int m = lane & 15;       // A-row (b%16) and B-col (o)

    // 8 tiles for Y=0..7 start at dxdy = dx*15 + (7-y), contiguous.
    const f16* wbase = W_h + (size_t)(dx * 15 + 7 - y) * 16384;

    // ---- stage tile Y=0 into buffer 0 ----
    #pragma unroll
    for (int it = 0; it < 8; ++it) {
        const int idx = (it * 256 + t) * 8;          // 16 B granule
        __builtin_amdgcn_global_load_lds((gas1_t)(wbase + idx),
                                         (las3_t)&Wl[idx], 16, 0, 0);
    }

    // ---- a-rows (Y-invariant) + all 8 c-frags into registers ----
    f16x8 a0[4], a1[4], c0[8], c1[8];
    const int b0 = wave * 32 + m;
    const int b1 = b0 + 16;
    {
        const f16* ar0 = inp_h + ((b0 * 8 + x) * 8 + y) * 32;
        const f16* ar1 = inp_h + ((b1 * 8 + x) * 8 + y) * 32;
        #pragma unroll
        for (int g = 0; g < 4; ++g) {
            a0[g] = *(const f16x8*)(ar0 + g * 8);
            a1[g] = *(const f16x8*)(ar1 + g * 8);
        }
        const f16* cr0 = inp_h + (b0 * 8 + X) * 256 + quad * 8;  // Y=0 row
        const f16* cr1 = inp_h + (b1 * 8 + X) * 256 + quad * 8;
        #pragma unroll
        for (int Yi = 0; Yi < 8; ++Yi) {
            c0[Yi] = *(const f16x8*)(cr0 + Yi * 32);
            c1[Yi] = *(const f16x8*)(cr1 + Yi * 32);
        }
    }

    __syncthreads();   // drains vmcnt -> tile 0 in LDS

    const int bid_base = ((x * 8 + y) * 8 + X) * 8;   // bid = bid_base + Y

    #pragma unroll     // full unroll: keeps c0[Y]/c1[Y] statically indexed
    for (int Y = 0; Y < 8; ++Y) {
        const int cur = Y & 1;

        // ---- issue prefetch of tile Y+1 into the other buffer ----
        if (Y < 7) {
            const f16* nbase = wbase + (size_t)(Y + 1) * 16384;
            f16* ldst = Wl + (cur ^ 1) * 16384;
            #pragma unroll
            for (int it = 0; it < 8; ++it) {
                const int idx = (it * 256 + t) * 8;
                __builtin_amdgcn_global_load_lds((gas1_t)(nbase + idx),
                                                 (las3_t)&ldst[idx], 16, 0, 0);
            }
        }

        // ---- K-loop: 32 steps, 2-deep bfrag prefetch ----
        f32x4 acc0 = {0.f, 0.f, 0.f, 0.f};
        f32x4 acc1 = {0.f, 0.f, 0.f, 0.f};
        const f16* wl = Wl + cur * 16384 + m * 32 + quad * 8;
        f16x8 bfrag = *(const f16x8*)(wl);               // kb = 0
        #pragma unroll
        for (int kb = 0; kb < 32; ++kb) {
            const f16x8 bcur = bfrag;
            if (kb < 31)
                bfrag = *(const f16x8*)(wl + (kb + 1) * 512);
            const f16 av0 = a0[kb >> 3][kb & 7];
            const f16 av1 = a1[kb >> 3][kb & 7];
            const f16x8 af0 = c0[Y] * av0;   // P[b, kb*32 + quad*8 + r]
            const f16x8 af1 = c1[Y] * av1;
            acc0 = __builtin_amdgcn_mfma_f32_16x16x32_f16(af0, bcur, acc0, 0, 0, 0);
            acc1 = __builtin_amdgcn_mfma_f32_16x16x32_f16(af1, bcur, acc1, 0, 0, 0);
        }

        // ---- stage results into obuf: chunk l = b*8 + ypar*4 + (o>>2) ----
        const int dxdy = dx * 15 + (Y - y + 7);
        const float bv = bias[dxdy * 16 + m];
        const int ypar = Y & 1;
        const int osub = (m >> 2) * 4 + (m & 3);   // (oq)*4 + lane-in-chunk
        #pragma unroll
        for (int r = 0; r < 4; ++r) {
            const int bb = wave * 32 + quad * 4 + r;
            obuf[(bb * 8 + ypar * 4) * 4 + osub]        = acc0[r] + bv;
            obuf[((bb + 16) * 8 + ypar * 4) * 4 + osub] = acc1[r] + bv;
        }

        __syncthreads();   // obuf visible; vmcnt drained -> tile Y+1 ready

        // ---- at odd Y: flush pair (Y-1, Y) as full 128 B lines ----
        if (ypar == 1) {
            const float4* ob4 = (const float4*)obuf;
            #pragma unroll
            for (int k = 0; k < 4; ++k) {
                const int c = k * 256 + t;            // 0..1023
                const int bb = c >> 3, yp = (c >> 2) & 1, oq = c & 3;
                const float4 v = ob4[c];
                *(float4*)(out + ((size_t)bb * 4096 + bid_base + (Y - 1) + yp) * 16
                           + oq * 4) = v;
            }
            __syncthreads();   // guard obuf reuse by next (even) Y
        }
    }
}

extern "C" void kernel_launch(void* const* d_in, const int* in_sizes, int n_in,
                              void* d_out, int out_size, void* d_ws, size_t ws_size,
                              hipStream_t stream)
{
    const float* inp  = (const float*)d_in[0];  // (128,8,8,32)
    const float* W    = (const float*)d_in[1];  // (15,15,16,32,32)
    const float* bias = (const float*)d_in[2];  // (15,15,16)
    float* out = (float*)d_out;

    f16* W_h   = (f16*)d_ws;                         // 7,372,800 halves
    f16* inp_h = (f16*)d_ws + (size_t)WGRAN * 8;     //   262,144 halves

    hipLaunchKernelGGL(convert_kernel, dim3((WGRAN + IGRAN) / 256), dim3(256), 0,
                       stream, W, inp, W_h, inp_h);
    hipLaunchKernelGGL(rel_mfma6, dim3(512), dim3(256), 81920, stream,
                       W_h, inp_h, bias, out);
}